// Round 1
// baseline (279.793 us; speedup 1.0000x reference)
//
#include <hip/hip_runtime.h>
#include <math.h>

#define NPTS 8192
#define KNN 32

typedef unsigned int uint;
typedef unsigned long long u64;

// ---- workspace layout (bytes) ----
#define OFF_PTS4 0                      // float4[N]            131072
#define OFF_WC   131072                 // float[128*32]        16384
#define OFF_BC   147456                 // float[128]           512
#define OFF_WPC  147968                 // float[128*3]         1536
#define OFF_BPC  149504                 // float[128]           512
#define OFF_G    150016                 // float[N*128]         4194304
#define OFF_IDX  4344320                // uint[N*32]           1048576
#define OFF_FT   5392896                // float[256*N]         8388608
// total 13781504 bytes

// ---------------------------------------------------------------------------
// pts4 = (x, y, z, x^2+y^2+z^2)
__global__ void k_prep(const float* __restrict__ cloud, float4* __restrict__ pts4) {
    int n = blockIdx.x * 256 + threadIdx.x;
    float x = cloud[n * 3 + 0], y = cloud[n * 3 + 1], z = cloud[n * 3 + 2];
    float sq = fmaf(x, x, fmaf(y, y, z * z));
    pts4[n] = make_float4(x, y, z, sq);
}

// ---------------------------------------------------------------------------
// Collapse the bias-free-nonlinearity MLP chains:
//   Wc = W2@W1 [128,32], bc = W2@b1+b2 ; Wpc = Wp2@Wp1 [128,3], bpc = Wp2@bp1+bp2
__global__ void k_combine(const float* __restrict__ W1, const float* __restrict__ b1,
                          const float* __restrict__ W2, const float* __restrict__ b2,
                          const float* __restrict__ Wp1, const float* __restrict__ bp1,
                          const float* __restrict__ Wp2, const float* __restrict__ bp2,
                          float* __restrict__ Wc, float* __restrict__ bc,
                          float* __restrict__ Wpc, float* __restrict__ bpc) {
    int t = threadIdx.x;
    int d = t & 127;
    int part = t >> 7;           // 0..7
    if (part < 4) {
        for (int c = part * 8; c < part * 8 + 8; ++c) {
            float a = 0.f;
            for (int o = 0; o < 64; ++o) a = fmaf(W2[d * 64 + o], W1[o * 32 + c], a);
            Wc[d * 32 + c] = a;
        }
    } else if (part == 4) {
        float a = b2[d];
        for (int o = 0; o < 64; ++o) a = fmaf(W2[d * 64 + o], b1[o], a);
        bc[d] = a;
    } else if (part == 5) {
        for (int c = 0; c < 3; ++c) {
            float a = 0.f;
            for (int o = 0; o < 64; ++o) a = fmaf(Wp2[d * 64 + o], Wp1[o * 3 + c], a);
            Wpc[d * 3 + c] = a;
        }
    } else if (part == 6) {
        float a = bp2[d];
        for (int o = 0; o < 64; ++o) a = fmaf(Wp2[d * 64 + o], bp1[o], a);
        bpc[d] = a;
    }
}

// ---------------------------------------------------------------------------
// g[n][d] = sum_c Wc[d][c] * feats[n][c] + bc[d]   (feats[n][c] = img_feat[c*N+n])
__global__ void k_gfeat(const float* __restrict__ img_feat, const float* __restrict__ Wc,
                        const float* __restrict__ bc, float* __restrict__ g) {
    __shared__ float wcs[128 * 33];   // padded rows: bank-conflict-free
    __shared__ float bcs[128];
    __shared__ float ft[32][16];
    int t = threadIdx.x;
    int n0 = blockIdx.x * 16;
    for (int i = t; i < 128 * 32; i += 256) { int dd = i >> 5, cc = i & 31; wcs[dd * 33 + cc] = Wc[i]; }
    if (t < 128) bcs[t] = bc[t];
    for (int i = t; i < 32 * 16; i += 256) { int cc = i >> 4, nn = i & 15; ft[cc][nn] = img_feat[cc * NPTS + n0 + nn]; }
    __syncthreads();
    int d = t & 127;
    int ng = t >> 7;
    for (int nl = ng * 8; nl < ng * 8 + 8; ++nl) {
        float a = bcs[d];
#pragma unroll
        for (int c = 0; c < 32; ++c) a = fmaf(wcs[d * 33 + c], ft[c][nl], a);
        g[(n0 + nl) * 128 + d] = a;
    }
}

// ---------------------------------------------------------------------------
// Exact KNN via per-wave radix/histogram select.
// block = 512 threads = 8 waves = 8 queries. Grid = N/8.
#define SPILL_CAP 224
__launch_bounds__(512)
__global__ void k_knn(const float4* __restrict__ pts4, uint* __restrict__ knn_idx) {
    __shared__ float4 tile[1024];          // 16 KB
    __shared__ uint hist[8][1024];         // 32 KB
    __shared__ u64 spill[8][SPILL_CAP];    // 14 KB
    __shared__ uint scnt[8];

    int t = threadIdx.x;
    int w = t >> 6;
    int lane = t & 63;
    int q = blockIdx.x * 8 + w;
    float4 qp = pts4[q];

    for (int i = t; i < 8 * 1024; i += 512) ((uint*)hist)[i] = 0;
    if (lane == 0) scnt[w] = 0;
    __syncthreads();

    // ---- pass 1: histogram of sortable keys ----
    for (int tt = 0; tt < 8; ++tt) {
        for (int i = t; i < 1024; i += 512) tile[i] = pts4[tt * 1024 + i];
        __syncthreads();
        for (int c = lane; c < 1024; c += 64) {
            float4 p = tile[c];
            float dot = fmaf(qp.x, p.x, fmaf(qp.y, p.y, qp.z * p.z));
            float d2 = (qp.w + p.w) - 2.0f * dot;
            uint bits = __float_as_uint(d2);
            uint key = bits ^ (0x80000000u | (uint)((int)bits >> 31));
            atomicAdd(&hist[w][key >> 22], 1u);
        }
        __syncthreads();
    }

    // ---- per-wave prefix scan: find bin B where cumulative count reaches K ----
    uint base = lane * 16;
    uint s16 = 0;
    for (int b = 0; b < 16; ++b) s16 += hist[w][base + b];
    uint x = s16;
    for (int off = 1; off < 64; off <<= 1) {
        uint y = __shfl_up(x, off);
        if (lane >= off) x += y;
    }
    uint excl = x - s16;
    bool cross = (excl < KNN) && (excl + s16 >= KNN);
    u64 mask = __ballot(cross);
    int src = __ffsll((unsigned long long)mask) - 1;
    uint Bl = 0;
    if (cross) {
        uint cum = excl;
        for (int b = 0; b < 16; ++b) {
            uint h = hist[w][base + b];
            if (cum + h >= KNN) { Bl = base + b; break; }
            cum += h;
        }
    }
    uint B = __shfl(Bl, src);
    __syncthreads();

    // ---- pass 2: collect all candidates with bin <= B ----
    for (int tt = 0; tt < 8; ++tt) {
        for (int i = t; i < 1024; i += 512) tile[i] = pts4[tt * 1024 + i];
        __syncthreads();
        for (int c = lane; c < 1024; c += 64) {
            float4 p = tile[c];
            float dot = fmaf(qp.x, p.x, fmaf(qp.y, p.y, qp.z * p.z));
            float d2 = (qp.w + p.w) - 2.0f * dot;
            uint bits = __float_as_uint(d2);
            uint key = bits ^ (0x80000000u | (uint)((int)bits >> 31));
            if ((key >> 22) <= B) {
                uint pos = atomicAdd(&scnt[w], 1u);
                if (pos < SPILL_CAP) spill[w][pos] = ((u64)key << 32) | (uint)(tt * 1024 + c);
            }
        }
        __syncthreads();
    }

    // ---- wave-parallel exact select of 32 smallest (key, idx) ----
    uint cnt = scnt[w];
    if (cnt > SPILL_CAP) cnt = SPILL_CAP;
    u64 e0 = (lane < cnt) ? spill[w][lane] : ~0ull;
    u64 e1 = (lane + 64 < cnt) ? spill[w][lane + 64] : ~0ull;
    u64 e2 = (lane + 128 < cnt) ? spill[w][lane + 128] : ~0ull;
    u64 e3 = (lane + 192 < cnt) ? spill[w][lane + 192] : ~0ull;
    for (int it = 0; it < KNN; ++it) {
        u64 m = e0 < e1 ? e0 : e1;
        u64 m2 = e2 < e3 ? e2 : e3;
        if (m2 < m) m = m2;
        u64 r = m;
        for (int off = 32; off >= 1; off >>= 1) {
            u64 o = __shfl_xor(r, off);
            if (o < r) r = o;
        }
        if (e0 == r) e0 = ~0ull;
        else if (e1 == r) e1 = ~0ull;
        else if (e2 == r) e2 = ~0ull;
        else if (e3 == r) e3 = ~0ull;
        if (lane == 0) knn_idx[q * KNN + it] = (uint)r;
    }
}

// ---------------------------------------------------------------------------
// wave-per-query: softmax weights + weighted maxpool over g + point branch.
// Writes F transposed: Ft[c][n], c in [0,256).
__global__ void k_surpc(const float4* __restrict__ pts4, const uint* __restrict__ knn_idx,
                        const float* __restrict__ g, const float* __restrict__ Wpc,
                        const float* __restrict__ bpc, float* __restrict__ Ft) {
    int t = threadIdx.x;
    int w = t >> 6;
    int lane = t & 63;
    int q = blockIdx.x * 4 + w;
    int k = lane & 31;
    uint j = knn_idx[q * KNN + k];
    float4 qp = pts4[q];
    float4 pj = pts4[j];
    float dx = qp.x - pj.x, dy = qp.y - pj.y, dz = qp.z - pj.z;
    float dist = sqrtf(fmaf(dx, dx, fmaf(dy, dy, dz * dz)));
    float dmin = dist;
    for (int off = 16; off >= 1; off >>= 1) dmin = fminf(dmin, __shfl_xor(dmin, off));
    float e = expf(dmin - dist);
    float S = e;
    for (int off = 16; off >= 1; off >>= 1) S += __shfl_xor(S, off);

    int d0 = lane * 2;
    float m0 = -INFINITY, m1 = -INFINITY;
#pragma unroll 8
    for (int kk = 0; kk < 32; ++kk) {
        float ek = __shfl(e, kk);
        int jk = __shfl((int)j, kk);
        float2 gv = *(const float2*)&g[(uint)jk * 128 + d0];
        m0 = fmaxf(m0, ek * gv.x);
        m1 = fmaxf(m1, ek * gv.y);
    }
    float inv = 1.0f / S;
    float s0 = m0 * inv, s1 = m1 * inv;

    float p0 = bpc[d0 + 0];
    p0 = fmaf(Wpc[(d0 + 0) * 3 + 0], qp.x, p0);
    p0 = fmaf(Wpc[(d0 + 0) * 3 + 1], qp.y, p0);
    p0 = fmaf(Wpc[(d0 + 0) * 3 + 2], qp.z, p0);
    float p1 = bpc[d0 + 1];
    p1 = fmaf(Wpc[(d0 + 1) * 3 + 0], qp.x, p1);
    p1 = fmaf(Wpc[(d0 + 1) * 3 + 1], qp.y, p1);
    p1 = fmaf(Wpc[(d0 + 1) * 3 + 2], qp.z, p1);

    Ft[(d0 + 0) * NPTS + q] = s0;
    Ft[(d0 + 1) * NPTS + q] = s1;
    Ft[(128 + d0 + 0) * NPTS + q] = p0;
    Ft[(128 + d0 + 1) * NPTS + q] = p1;
}

// ---------------------------------------------------------------------------
// out[d][n] = sum_c Wf[d][c] * Ft[c][n] + bf[d]   (register-tiled fp32 GEMM)
// block: 256 threads -> 32 n x 128 d. grid = N/32 = 256 blocks.
__global__ void k_final(const float* __restrict__ Ft, const float* __restrict__ Wf,
                        const float* __restrict__ bf, float* __restrict__ out) {
    __shared__ float Fs[256 * 32];     // 32 KB, [k][n]
    __shared__ float wfs[32 * 132];    // 16.9 KB, [kk][d] padded
    int t = threadIdx.x;
    int tn = t & 15;
    int td = t >> 4;
    int n0 = blockIdx.x * 32;
    int d0 = td * 8;

    for (int i = t; i < 256 * 32; i += 256) {
        int nn = i & 31, kk = i >> 5;
        Fs[kk * 32 + nn] = Ft[kk * NPTS + n0 + nn];
    }

    float acc[2][8];
#pragma unroll
    for (int a = 0; a < 2; ++a)
#pragma unroll
        for (int b = 0; b < 8; ++b) acc[a][b] = 0.f;

    for (int kc = 0; kc < 8; ++kc) {
        __syncthreads();
        for (int i = t; i < 32 * 128; i += 256) {
            int kk = i & 31, d = i >> 5;
            wfs[kk * 132 + d] = Wf[d * 256 + kc * 32 + kk];
        }
        __syncthreads();
#pragma unroll 4
        for (int kk = 0; kk < 32; ++kk) {
            int k = kc * 32 + kk;
            float2 f = *(const float2*)&Fs[k * 32 + tn * 2];
            const float* wr = &wfs[kk * 132 + d0];
            float4 wa = *(const float4*)wr;
            float4 wb = *(const float4*)(wr + 4);
            acc[0][0] = fmaf(f.x, wa.x, acc[0][0]); acc[1][0] = fmaf(f.y, wa.x, acc[1][0]);
            acc[0][1] = fmaf(f.x, wa.y, acc[0][1]); acc[1][1] = fmaf(f.y, wa.y, acc[1][1]);
            acc[0][2] = fmaf(f.x, wa.z, acc[0][2]); acc[1][2] = fmaf(f.y, wa.z, acc[1][2]);
            acc[0][3] = fmaf(f.x, wa.w, acc[0][3]); acc[1][3] = fmaf(f.y, wa.w, acc[1][3]);
            acc[0][4] = fmaf(f.x, wb.x, acc[0][4]); acc[1][4] = fmaf(f.y, wb.x, acc[1][4]);
            acc[0][5] = fmaf(f.x, wb.y, acc[0][5]); acc[1][5] = fmaf(f.y, wb.y, acc[1][5]);
            acc[0][6] = fmaf(f.x, wb.z, acc[0][6]); acc[1][6] = fmaf(f.y, wb.z, acc[1][6]);
            acc[0][7] = fmaf(f.x, wb.w, acc[0][7]); acc[1][7] = fmaf(f.y, wb.w, acc[1][7]);
        }
    }
#pragma unroll
    for (int dd = 0; dd < 8; ++dd) {
        int d = d0 + dd;
        float b = bf[d];
        *(float2*)&out[d * NPTS + n0 + tn * 2] = make_float2(acc[0][dd] + b, acc[1][dd] + b);
    }
}

// ---------------------------------------------------------------------------
extern "C" void kernel_launch(void* const* d_in, const int* in_sizes, int n_in,
                              void* d_out, int out_size, void* d_ws, size_t ws_size,
                              hipStream_t stream) {
    const float* img_feat = (const float*)d_in[0];
    const float* cloud    = (const float*)d_in[1];
    const float* W1  = (const float*)d_in[2];
    const float* b1  = (const float*)d_in[3];
    const float* W2  = (const float*)d_in[4];
    const float* b2  = (const float*)d_in[5];
    const float* Wp1 = (const float*)d_in[6];
    const float* bp1 = (const float*)d_in[7];
    const float* Wp2 = (const float*)d_in[8];
    const float* bp2 = (const float*)d_in[9];
    const float* Wf  = (const float*)d_in[10];
    const float* bf  = (const float*)d_in[11];
    float* out = (float*)d_out;

    char* ws = (char*)d_ws;
    float4* pts4 = (float4*)(ws + OFF_PTS4);
    float* Wc  = (float*)(ws + OFF_WC);
    float* bc  = (float*)(ws + OFF_BC);
    float* Wpc = (float*)(ws + OFF_WPC);
    float* bpc = (float*)(ws + OFF_BPC);
    float* g   = (float*)(ws + OFF_G);
    uint* knn_idx = (uint*)(ws + OFF_IDX);
    float* Ft  = (float*)(ws + OFF_FT);

    k_prep<<<NPTS / 256, 256, 0, stream>>>(cloud, pts4);
    k_combine<<<1, 1024, 0, stream>>>(W1, b1, W2, b2, Wp1, bp1, Wp2, bp2, Wc, bc, Wpc, bpc);
    k_gfeat<<<NPTS / 16, 256, 0, stream>>>(img_feat, Wc, bc, g);
    k_knn<<<NPTS / 8, 512, 0, stream>>>(pts4, knn_idx);
    k_surpc<<<NPTS / 4, 256, 0, stream>>>(pts4, knn_idx, g, Wpc, bpc, Ft);
    k_final<<<NPTS / 32, 256, 0, stream>>>(Ft, Wf, bf, out);
}

// Round 2
// 171.873 us; speedup vs baseline: 1.6279x; 1.6279x over previous
//
#include <hip/hip_runtime.h>
#include <math.h>

#define NPTS 8192
#define KNN 32

typedef unsigned int uint;
typedef unsigned long long u64;

// ---- workspace layout (bytes) ----
#define OFF_PTS4 0                      // float4[N]            131072
#define OFF_WC   131072                 // float[128*32]        16384
#define OFF_BC   147456                 // float[128]           512
#define OFF_WPC  147968                 // float[128*3]         1536
#define OFF_BPC  149504                 // float[128]           512
#define OFF_G    150016                 // float[N*128]         4194304
#define OFF_IDX  4344320                // uint[N*32]           1048576
#define OFF_FT   5392896                // float[256*N]         8388608
// total 13781504 bytes

// Shared distance arithmetic: MUST be identical in every pass (prepass
// guarantee + pass-1/refine consistency rely on bit-identical d2 per pair).
__device__ __forceinline__ float dist2f(const float4 q, const float4 p) {
    float dot = fmaf(q.x, p.x, fmaf(q.y, p.y, q.z * p.z));
    return (q.w + p.w) - 2.0f * dot;
}
__device__ __forceinline__ uint fkey(float d) {
    uint bits = __float_as_uint(d);
    return bits ^ (0x80000000u | (uint)((int)bits >> 31));  // monotone sortable
}

// ---------------------------------------------------------------------------
__global__ void k_prep(const float* __restrict__ cloud, float4* __restrict__ pts4) {
    int n = blockIdx.x * 256 + threadIdx.x;
    float x = cloud[n * 3 + 0], y = cloud[n * 3 + 1], z = cloud[n * 3 + 2];
    float sq = fmaf(x, x, fmaf(y, y, z * z));
    pts4[n] = make_float4(x, y, z, sq);
}

// ---------------------------------------------------------------------------
// Parallel collapse of the bias-free MLP chains (one output element / thread).
//   Wc = W2@W1 [128,32], bc = W2@b1+b2 ; Wpc = Wp2@Wp1 [128,3], bpc = Wp2@bp1+bp2
__global__ void k_combine(const float* __restrict__ W1, const float* __restrict__ b1,
                          const float* __restrict__ W2, const float* __restrict__ b2,
                          const float* __restrict__ Wp1, const float* __restrict__ bp1,
                          const float* __restrict__ Wp2, const float* __restrict__ bp2,
                          float* __restrict__ Wc, float* __restrict__ bc,
                          float* __restrict__ Wpc, float* __restrict__ bpc) {
    int id = blockIdx.x * 256 + threadIdx.x;
    if (id < 4096) {                 // Wc[d][c]
        int d = id >> 5, c = id & 31;
        float a0 = 0.f, a1 = 0.f;
        for (int o = 0; o < 64; o += 2) {
            a0 = fmaf(W2[d * 64 + o], W1[o * 32 + c], a0);
            a1 = fmaf(W2[d * 64 + o + 1], W1[(o + 1) * 32 + c], a1);
        }
        Wc[id] = a0 + a1;
    } else if (id < 4224) {          // bc[d]
        int d = id - 4096;
        float a = b2[d];
        for (int o = 0; o < 64; ++o) a = fmaf(W2[d * 64 + o], b1[o], a);
        bc[d] = a;
    } else if (id < 4608) {          // Wpc[d][c]
        int i = id - 4224, d = i / 3, c = i - d * 3;
        float a = 0.f;
        for (int o = 0; o < 64; ++o) a = fmaf(Wp2[d * 64 + o], Wp1[o * 3 + c], a);
        Wpc[i] = a;
    } else if (id < 4736) {          // bpc[d]
        int d = id - 4608;
        float a = bp2[d];
        for (int o = 0; o < 64; ++o) a = fmaf(Wp2[d * 64 + o], bp1[o], a);
        bpc[d] = a;
    }
}

// ---------------------------------------------------------------------------
// g[n][d] = sum_c Wc[d][c] * feats[n][c] + bc[d]   (feats[n][c] = img_feat[c*N+n])
__global__ void k_gfeat(const float* __restrict__ img_feat, const float* __restrict__ Wc,
                        const float* __restrict__ bc, float* __restrict__ g) {
    __shared__ float wcs[128 * 33];
    __shared__ float bcs[128];
    __shared__ float ft[32][16];
    int t = threadIdx.x;
    int n0 = blockIdx.x * 16;
    for (int i = t; i < 128 * 32; i += 256) { int dd = i >> 5, cc = i & 31; wcs[dd * 33 + cc] = Wc[i]; }
    if (t < 128) bcs[t] = bc[t];
    for (int i = t; i < 32 * 16; i += 256) { int cc = i >> 4, nn = i & 15; ft[cc][nn] = img_feat[cc * NPTS + n0 + nn]; }
    __syncthreads();
    int d = t & 127;
    int ng = t >> 7;
    for (int nl = ng * 8; nl < ng * 8 + 8; ++nl) {
        float a = bcs[d];
#pragma unroll
        for (int c = 0; c < 32; ++c) a = fmaf(wcs[d * 33 + c], ft[c][nl], a);
        g[(n0 + nl) * 128 + d] = a;
    }
}

// ---------------------------------------------------------------------------
// Exact KNN, v2: prepass threshold -> single spill sweep -> fine-bin refine.
// block = 512 threads = 8 waves = 8 queries. Grid = N/8.
// Output set is unordered (downstream softmax/max/gather are permutation-invariant).
#define SPILL_CAP 384
__launch_bounds__(512)
__global__ void k_knn(const float4* __restrict__ pts4, uint* __restrict__ knn_idx) {
    __shared__ float4 tile[1024];          // 16 KB
    __shared__ u64 spill[8][SPILL_CAP];    // 24 KB
    __shared__ uint hist[8][256];          // 8 KB
    __shared__ uint scnt[8], dcnt[8];

    int t = threadIdx.x;
    int w = t >> 6;
    int lane = t & 63;
    int q = blockIdx.x * 8 + w;
    float4 qp = pts4[q];

    // zero own (per-wave private) hist + counters — no cross-wave sync needed
#pragma unroll
    for (int i = 0; i < 4; ++i) hist[w][lane * 4 + i] = 0;
    if (lane == 0) { scnt[w] = 0; dcnt[w] = 0; }

    // ---- prepass: per-lane min over 32 disjoint samples (candidates 0..2047) ----
    float mn = 3.4e38f;
    for (int s = 0; s < 32; ++s) {
        float4 p = pts4[lane + 64 * s];
        mn = fminf(mn, dist2f(qp, p));
    }
    // safety threshold: max of the 64 lane-minima (trivially >= 64 candidates below)
    float tmax = mn;
    for (int off = 32; off >= 1; off >>= 1) tmax = fmaxf(tmax, __shfl_xor(tmax, off));
    // bitonic sort the 64 minima ascending; T0 = 32nd smallest
    float v = mn;
    for (int k = 2; k <= 64; k <<= 1)
        for (int j = k >> 1; j > 0; j >>= 1) {
            float o = __shfl_xor(v, j);
            bool keepMin = (((lane & j) == 0) == ((lane & k) == 0));
            v = keepMin ? fminf(v, o) : fmaxf(v, o);
        }
    float nxt = __shfl_down(v, 1);
    bool bad = (lane < 63) && (v > nxt);
    float T0 = __shfl(v, 31);
    if (__ballot(bad) != 0ull) T0 = tmax;   // fall back if sort ever misbehaves
    uint K0 = fkey(T0);

    __syncthreads();

    // ---- single sweep: spill every candidate with d2 <= T0 (~175 expected) ----
    for (int tt = 0; tt < 8; ++tt) {
        for (int i = t; i < 1024; i += 512) tile[i] = pts4[tt * 1024 + i];
        __syncthreads();
        for (int c = lane; c < 1024; c += 64) {
            float4 p = tile[c];
            float d2 = dist2f(qp, p);
            if (d2 <= T0) {
                uint key = fkey(d2);
                uint pos = atomicAdd(&scnt[w], 1u);
                if (pos < SPILL_CAP) spill[w][pos] = ((u64)key << 32) | (uint)(tt * 1024 + c);
            }
        }
        __syncthreads();
    }

    // ---- refine: fine linear-key bins over [K0 - 2^24, K0] (~1/128 octave) ----
    uint cnt = scnt[w];
    if (cnt > SPILL_CAP) cnt = SPILL_CAP;
    uint base = K0 - (1u << 24);

    u64 sp0 = (lane + 0   < (int)cnt) ? spill[w][lane + 0]   : ~0ull;
    u64 sp1 = (lane + 64  < (int)cnt) ? spill[w][lane + 64]  : ~0ull;
    u64 sp2 = (lane + 128 < (int)cnt) ? spill[w][lane + 128] : ~0ull;
    u64 sp3 = (lane + 192 < (int)cnt) ? spill[w][lane + 192] : ~0ull;
    u64 sp4 = (lane + 256 < (int)cnt) ? spill[w][lane + 256] : ~0ull;
    u64 sp5 = (lane + 320 < (int)cnt) ? spill[w][lane + 320] : ~0ull;

#define BINOF(e) ({ uint k32_ = (uint)((e) >> 32); uint rel_ = k32_ - base; \
                    uint b_ = (k32_ < base) ? 0u : (rel_ >> 16); b_ > 255u ? 255u : b_; })

    if (sp0 != ~0ull) atomicAdd(&hist[w][BINOF(sp0)], 1u);
    if (sp1 != ~0ull) atomicAdd(&hist[w][BINOF(sp1)], 1u);
    if (sp2 != ~0ull) atomicAdd(&hist[w][BINOF(sp2)], 1u);
    if (sp3 != ~0ull) atomicAdd(&hist[w][BINOF(sp3)], 1u);
    if (sp4 != ~0ull) atomicAdd(&hist[w][BINOF(sp4)], 1u);
    if (sp5 != ~0ull) atomicAdd(&hist[w][BINOF(sp5)], 1u);

    // per-wave scan of 256 bins (4 per lane) to find crossing bin B and nbelow
    uint b0 = hist[w][lane * 4 + 0], b1 = hist[w][lane * 4 + 1];
    uint b2 = hist[w][lane * 4 + 2], b3 = hist[w][lane * 4 + 3];
    uint s4 = b0 + b1 + b2 + b3;
    uint x = s4;
    for (int off = 1; off < 64; off <<= 1) {
        uint y = __shfl_up(x, off);
        if (lane >= off) x += y;
    }
    uint excl = x - s4;
    bool cross = (excl < KNN) && (excl + s4 >= KNN);
    u64 mk = __ballot(cross);
    int src = __ffsll((unsigned long long)mk) - 1;
    uint Bl = 0, nbl = 0;
    if (cross) {
        uint cum = excl;
        if (cum + b0 >= KNN)                { Bl = lane * 4 + 0; nbl = cum; }
        else if (cum + b0 + b1 >= KNN)      { Bl = lane * 4 + 1; nbl = cum + b0; }
        else if (cum + b0 + b1 + b2 >= KNN) { Bl = lane * 4 + 2; nbl = cum + b0 + b1; }
        else                                { Bl = lane * 4 + 3; nbl = cum + b0 + b1 + b2; }
    }
    uint B = __shfl(Bl, src);
    uint nbelow = __shfl(nbl, src);
    uint need = KNN - nbelow;

    // direct-write everything strictly below bin B; keep bin==B for exact select
#define PROCSP(r) { if (sp##r != ~0ull) { uint b_ = BINOF(sp##r); \
        if (b_ < B) { uint pos = atomicAdd(&dcnt[w], 1u); \
                      knn_idx[q * KNN + pos] = (uint)sp##r; sp##r = ~0ull; } \
        else if (b_ > B) sp##r = ~0ull; } }
    PROCSP(0) PROCSP(1) PROCSP(2) PROCSP(3) PROCSP(4) PROCSP(5)

    // exact (key,idx)-ordered select of the remaining `need` (typically 1-3)
    uint outbase = q * KNN + nbelow;
    for (uint it = 0; it < need; ++it) {
        u64 m = sp0;
        if (sp1 < m) m = sp1;
        if (sp2 < m) m = sp2;
        if (sp3 < m) m = sp3;
        if (sp4 < m) m = sp4;
        if (sp5 < m) m = sp5;
        u64 r = m;
        for (int off = 32; off >= 1; off >>= 1) {
            u64 o = __shfl_xor(r, off);
            if (o < r) r = o;
        }
        if (sp0 == r) sp0 = ~0ull;
        else if (sp1 == r) sp1 = ~0ull;
        else if (sp2 == r) sp2 = ~0ull;
        else if (sp3 == r) sp3 = ~0ull;
        else if (sp4 == r) sp4 = ~0ull;
        else if (sp5 == r) sp5 = ~0ull;
        if (lane == 0) knn_idx[outbase + it] = (uint)r;
    }
}

// ---------------------------------------------------------------------------
// wave-per-query: softmax weights + weighted maxpool over g + point branch.
__global__ void k_surpc(const float4* __restrict__ pts4, const uint* __restrict__ knn_idx,
                        const float* __restrict__ g, const float* __restrict__ Wpc,
                        const float* __restrict__ bpc, float* __restrict__ Ft) {
    int t = threadIdx.x;
    int w = t >> 6;
    int lane = t & 63;
    int q = blockIdx.x * 4 + w;
    int k = lane & 31;
    uint j = knn_idx[q * KNN + k];
    float4 qp = pts4[q];
    float4 pj = pts4[j];
    float dx = qp.x - pj.x, dy = qp.y - pj.y, dz = qp.z - pj.z;
    float dist = sqrtf(fmaf(dx, dx, fmaf(dy, dy, dz * dz)));
    float dmin = dist;
    for (int off = 16; off >= 1; off >>= 1) dmin = fminf(dmin, __shfl_xor(dmin, off));
    float e = expf(dmin - dist);
    float S = e;
    for (int off = 16; off >= 1; off >>= 1) S += __shfl_xor(S, off);

    int d0 = lane * 2;
    float m0 = -INFINITY, m1 = -INFINITY;
#pragma unroll 8
    for (int kk = 0; kk < 32; ++kk) {
        float ek = __shfl(e, kk);
        int jk = __shfl((int)j, kk);
        float2 gv = *(const float2*)&g[(uint)jk * 128 + d0];
        m0 = fmaxf(m0, ek * gv.x);
        m1 = fmaxf(m1, ek * gv.y);
    }
    float inv = 1.0f / S;
    float s0 = m0 * inv, s1 = m1 * inv;

    float p0 = bpc[d0 + 0];
    p0 = fmaf(Wpc[(d0 + 0) * 3 + 0], qp.x, p0);
    p0 = fmaf(Wpc[(d0 + 0) * 3 + 1], qp.y, p0);
    p0 = fmaf(Wpc[(d0 + 0) * 3 + 2], qp.z, p0);
    float p1 = bpc[d0 + 1];
    p1 = fmaf(Wpc[(d0 + 1) * 3 + 0], qp.x, p1);
    p1 = fmaf(Wpc[(d0 + 1) * 3 + 1], qp.y, p1);
    p1 = fmaf(Wpc[(d0 + 1) * 3 + 2], qp.z, p1);

    Ft[(d0 + 0) * NPTS + q] = s0;
    Ft[(d0 + 1) * NPTS + q] = s1;
    Ft[(128 + d0 + 0) * NPTS + q] = p0;
    Ft[(128 + d0 + 1) * NPTS + q] = p1;
}

// ---------------------------------------------------------------------------
// out[d][n] = sum_c Wf[d][c] * Ft[c][n] + bf[d]
__global__ void k_final(const float* __restrict__ Ft, const float* __restrict__ Wf,
                        const float* __restrict__ bf, float* __restrict__ out) {
    __shared__ float Fs[256 * 32];
    __shared__ float wfs[32 * 132];
    int t = threadIdx.x;
    int tn = t & 15;
    int td = t >> 4;
    int n0 = blockIdx.x * 32;
    int d0 = td * 8;

    for (int i = t; i < 256 * 32; i += 256) {
        int nn = i & 31, kk = i >> 5;
        Fs[kk * 32 + nn] = Ft[kk * NPTS + n0 + nn];
    }

    float acc[2][8];
#pragma unroll
    for (int a = 0; a < 2; ++a)
#pragma unroll
        for (int b = 0; b < 8; ++b) acc[a][b] = 0.f;

    for (int kc = 0; kc < 8; ++kc) {
        __syncthreads();
        for (int i = t; i < 32 * 128; i += 256) {
            int kk = i & 31, d = i >> 5;
            wfs[kk * 132 + d] = Wf[d * 256 + kc * 32 + kk];
        }
        __syncthreads();
#pragma unroll 4
        for (int kk = 0; kk < 32; ++kk) {
            int k = kc * 32 + kk;
            float2 f = *(const float2*)&Fs[k * 32 + tn * 2];
            const float* wr = &wfs[kk * 132 + d0];
            float4 wa = *(const float4*)wr;
            float4 wb = *(const float4*)(wr + 4);
            acc[0][0] = fmaf(f.x, wa.x, acc[0][0]); acc[1][0] = fmaf(f.y, wa.x, acc[1][0]);
            acc[0][1] = fmaf(f.x, wa.y, acc[0][1]); acc[1][1] = fmaf(f.y, wa.y, acc[1][1]);
            acc[0][2] = fmaf(f.x, wa.z, acc[0][2]); acc[1][2] = fmaf(f.y, wa.z, acc[1][2]);
            acc[0][3] = fmaf(f.x, wa.w, acc[0][3]); acc[1][3] = fmaf(f.y, wa.w, acc[1][3]);
            acc[0][4] = fmaf(f.x, wb.x, acc[0][4]); acc[1][4] = fmaf(f.y, wb.x, acc[1][4]);
            acc[0][5] = fmaf(f.x, wb.y, acc[0][5]); acc[1][5] = fmaf(f.y, wb.y, acc[1][5]);
            acc[0][6] = fmaf(f.x, wb.z, acc[0][6]); acc[1][6] = fmaf(f.y, wb.z, acc[1][6]);
            acc[0][7] = fmaf(f.x, wb.w, acc[0][7]); acc[1][7] = fmaf(f.y, wb.w, acc[1][7]);
        }
    }
#pragma unroll
    for (int dd = 0; dd < 8; ++dd) {
        int d = d0 + dd;
        float b = bf[d];
        *(float2*)&out[d * NPTS + n0 + tn * 2] = make_float2(acc[0][dd] + b, acc[1][dd] + b);
    }
}

// ---------------------------------------------------------------------------
extern "C" void kernel_launch(void* const* d_in, const int* in_sizes, int n_in,
                              void* d_out, int out_size, void* d_ws, size_t ws_size,
                              hipStream_t stream) {
    const float* img_feat = (const float*)d_in[0];
    const float* cloud    = (const float*)d_in[1];
    const float* W1  = (const float*)d_in[2];
    const float* b1  = (const float*)d_in[3];
    const float* W2  = (const float*)d_in[4];
    const float* b2  = (const float*)d_in[5];
    const float* Wp1 = (const float*)d_in[6];
    const float* bp1 = (const float*)d_in[7];
    const float* Wp2 = (const float*)d_in[8];
    const float* bp2 = (const float*)d_in[9];
    const float* Wf  = (const float*)d_in[10];
    const float* bf  = (const float*)d_in[11];
    float* out = (float*)d_out;

    char* ws = (char*)d_ws;
    float4* pts4 = (float4*)(ws + OFF_PTS4);
    float* Wc  = (float*)(ws + OFF_WC);
    float* bc  = (float*)(ws + OFF_BC);
    float* Wpc = (float*)(ws + OFF_WPC);
    float* bpc = (float*)(ws + OFF_BPC);
    float* g   = (float*)(ws + OFF_G);
    uint* knn_idx = (uint*)(ws + OFF_IDX);
    float* Ft  = (float*)(ws + OFF_FT);

    k_prep<<<NPTS / 256, 256, 0, stream>>>(cloud, pts4);
    k_combine<<<19, 256, 0, stream>>>(W1, b1, W2, b2, Wp1, bp1, Wp2, bp2, Wc, bc, Wpc, bpc);
    k_gfeat<<<NPTS / 16, 256, 0, stream>>>(img_feat, Wc, bc, g);
    k_knn<<<NPTS / 8, 512, 0, stream>>>(pts4, knn_idx);
    k_surpc<<<NPTS / 4, 256, 0, stream>>>(pts4, knn_idx, g, Wpc, bpc, Ft);
    k_final<<<NPTS / 32, 256, 0, stream>>>(Ft, Wf, bf, out);
}

// Round 3
// 115.827 us; speedup vs baseline: 2.4156x; 1.4839x over previous
//
#include <hip/hip_runtime.h>
#include <math.h>

#define NPTS 8192
#define KNN 32

typedef unsigned int uint;
typedef unsigned long long u64;

// ---- workspace layout (bytes) ----
#define OFF_PTS4 0                      // float4[N]            131072
#define OFF_WC   131072                 // float[128*32]        16384
#define OFF_BC   147456                 // float[128]           512
#define OFF_WPC  147968                 // float[128*3]         1536
#define OFF_BPC  149504                 // float[128]           512
#define OFF_G    150016                 // float[N*128]         4194304
#define OFF_IDX  4344320                // uint[N*32]           1048576
#define OFF_F    5392896                // float[N*256] row-major 8388608
// total 13781504 bytes

// Shared distance arithmetic: MUST be bit-identical in every pass (prepass
// threshold guarantee + sweep/refine key consistency).
__device__ __forceinline__ float dist2f(const float4 q, const float4 p) {
    float dot = fmaf(q.x, p.x, fmaf(q.y, p.y, q.z * p.z));
    return (q.w + p.w) - 2.0f * dot;
}
__device__ __forceinline__ uint fkey(float d) {
    uint bits = __float_as_uint(d);
    return bits ^ (0x80000000u | (uint)((int)bits >> 31));  // monotone sortable
}

// 32nd-smallest of the 64 lane values (bitonic sort + sortedness fallback)
__device__ __forceinline__ float thresh32(float mn, int lane) {
    float tmax = mn;
    for (int off = 32; off >= 1; off >>= 1) tmax = fmaxf(tmax, __shfl_xor(tmax, off));
    float v = mn;
    for (int k = 2; k <= 64; k <<= 1)
        for (int j = k >> 1; j > 0; j >>= 1) {
            float o = __shfl_xor(v, j);
            bool keepMin = (((lane & j) == 0) == ((lane & k) == 0));
            v = keepMin ? fminf(v, o) : fmaxf(v, o);
        }
    float nxt = __shfl_down(v, 1);
    bool bad = (lane < 63) && (v > nxt);
    float T = __shfl(v, 31);
    if (__ballot(bad) != 0ull) T = tmax;
    return T;
}

// ---------------------------------------------------------------------------
// Fused: blocks 0..31 build pts4; blocks 32..50 collapse the MLP chains.
__launch_bounds__(256)
__global__ void k_prep_combine(const float* __restrict__ cloud, float4* __restrict__ pts4,
                               const float* __restrict__ W1, const float* __restrict__ b1,
                               const float* __restrict__ W2, const float* __restrict__ b2,
                               const float* __restrict__ Wp1, const float* __restrict__ bp1,
                               const float* __restrict__ Wp2, const float* __restrict__ bp2,
                               float* __restrict__ Wc, float* __restrict__ bc,
                               float* __restrict__ Wpc, float* __restrict__ bpc) {
    int bid = blockIdx.x;
    int t = threadIdx.x;
    if (bid < 32) {
        int n = bid * 256 + t;
        float x = cloud[n * 3 + 0], y = cloud[n * 3 + 1], z = cloud[n * 3 + 2];
        float sq = fmaf(x, x, fmaf(y, y, z * z));
        pts4[n] = make_float4(x, y, z, sq);
        return;
    }
    int id = (bid - 32) * 256 + t;
    if (id < 4096) {                 // Wc[d][c] = sum_o W2[d][o] W1[o][c]
        int d = id >> 5, c = id & 31;
        float a0 = 0.f, a1 = 0.f;
        for (int o = 0; o < 64; o += 2) {
            a0 = fmaf(W2[d * 64 + o], W1[o * 32 + c], a0);
            a1 = fmaf(W2[d * 64 + o + 1], W1[(o + 1) * 32 + c], a1);
        }
        Wc[id] = a0 + a1;
    } else if (id < 4224) {          // bc[d]
        int d = id - 4096;
        float a = b2[d];
        for (int o = 0; o < 64; ++o) a = fmaf(W2[d * 64 + o], b1[o], a);
        bc[d] = a;
    } else if (id < 4608) {          // Wpc[d][c]
        int i = id - 4224, d = i / 3, c = i - d * 3;
        float a = 0.f;
        for (int o = 0; o < 64; ++o) a = fmaf(Wp2[d * 64 + o], Wp1[o * 3 + c], a);
        Wpc[i] = a;
    } else if (id < 4736) {          // bpc[d]
        int d = id - 4608;
        float a = bp2[d];
        for (int o = 0; o < 64; ++o) a = fmaf(Wp2[d * 64 + o], bp1[o], a);
        bpc[d] = a;
    }
}

// ---------------------------------------------------------------------------
// g[n][d] = sum_c Wc[d][c] * feats[n][c] + bc[d]   (feats[n][c] = img_feat[c*N+n])
__launch_bounds__(256)
__global__ void k_gfeat(const float* __restrict__ img_feat, const float* __restrict__ Wc,
                        const float* __restrict__ bc, float* __restrict__ g) {
    __shared__ float wcs[128 * 33];
    __shared__ float bcs[128];
    __shared__ float ft[32][16];
    int t = threadIdx.x;
    int n0 = blockIdx.x * 16;
    for (int i = t; i < 128 * 32; i += 256) { int dd = i >> 5, cc = i & 31; wcs[dd * 33 + cc] = Wc[i]; }
    if (t < 128) bcs[t] = bc[t];
    for (int i = t; i < 32 * 16; i += 256) { int cc = i >> 4, nn = i & 15; ft[cc][nn] = img_feat[cc * NPTS + n0 + nn]; }
    __syncthreads();
    int d = t & 127;
    int ng = t >> 7;
    for (int nl = ng * 8; nl < ng * 8 + 8; ++nl) {
        float a = bcs[d];
#pragma unroll
        for (int c = 0; c < 32; ++c) a = fmaf(wcs[d * 33 + c], ft[c][nl], a);
        g[(n0 + nl) * 128 + d] = a;
    }
}

// ---------------------------------------------------------------------------
// Exact KNN v3: 4 shared queries per block (256 thr = 4 waves); wave w sweeps
// candidates [w*2048,(w+1)*2048) for all 4 queries, direct from L2 (no tile
// LDS, no sweep barriers, no atomics). Per-(query,wave) spill segments keep
// everything deterministic. Refine: one wave per query.
#define CAPSEG 96
__launch_bounds__(256)
__global__ void k_knn(const float4* __restrict__ pts4, uint* __restrict__ knn_idx) {
    __shared__ uint spillIdx[4][4][CAPSEG];   // [q][seg(=sweep wave)][slot]  6 KB
    __shared__ uint segcnt[4][4];             // [q][seg]
    __shared__ uint hist[4][256];             // per refine-wave              4 KB

    int t = threadIdx.x, w = t >> 6, lane = t & 63;
    int qbase = blockIdx.x * 4;
    float4 q0 = pts4[qbase + 0], q1 = pts4[qbase + 1];
    float4 q2 = pts4[qbase + 2], q3 = pts4[qbase + 3];
    const u64 lmlt = (1ull << lane) - 1;

    // ---- prepass: per-lane min over samples 0..2047 (redundant across waves, L1/L2-hot)
    float mn0 = 3.4e38f, mn1 = 3.4e38f, mn2 = 3.4e38f, mn3 = 3.4e38f;
#pragma unroll 4
    for (int s = 0; s < 32; ++s) {
        float4 p = pts4[(s << 6) + lane];
        mn0 = fminf(mn0, dist2f(q0, p));
        mn1 = fminf(mn1, dist2f(q1, p));
        mn2 = fminf(mn2, dist2f(q2, p));
        mn3 = fminf(mn3, dist2f(q3, p));
    }
    float T0 = thresh32(mn0, lane), T1 = thresh32(mn1, lane);
    float T2 = thresh32(mn2, lane), T3 = thresh32(mn3, lane);

    // ---- sweep: wave-private ballot-compacted spill, no LDS staging ----
    uint c0 = 0, c1 = 0, c2 = 0, c3 = 0;
    int cbase = (w << 11) + lane;

#define SPQ(Q, TQ, CQ) { float d2_ = dist2f(q##Q, p); bool in_ = d2_ <= TQ; \
    u64 mk_ = __ballot(in_); \
    if (mk_) { uint pos_ = CQ + (uint)__popcll(mk_ & lmlt); \
        if (in_ && pos_ < CAPSEG) spillIdx[Q][w][pos_] = cidx; \
        CQ += (uint)__popcll(mk_); } }

#pragma unroll 2
    for (int it = 0; it < 32; ++it) {
        uint cidx = cbase + (it << 6);
        float4 p = pts4[cidx];
        SPQ(0, T0, c0)
        SPQ(1, T1, c1)
        SPQ(2, T2, c2)
        SPQ(3, T3, c3)
    }
    if (lane == 0) {
        segcnt[0][w] = c0; segcnt[1][w] = c1; segcnt[2][w] = c2; segcnt[3][w] = c3;
    }
    __syncthreads();

    // ---- refine: wave w handles query qbase+w ----
    float4 qw = w == 0 ? q0 : w == 1 ? q1 : w == 2 ? q2 : q3;
    float Tw  = w == 0 ? T0 : w == 1 ? T1 : w == 2 ? T2 : T3;
    uint K0 = fkey(Tw);
    uint kbase = K0 - (1u << 24);

    for (int i = lane; i < 256; i += 64) hist[w][i] = 0;

    u64 sp[8];
    uint bn[8];
#pragma unroll
    for (int s = 0; s < 4; ++s) {
        uint sc = segcnt[w][s];
        if (sc > CAPSEG) sc = CAPSEG;
#pragma unroll
        for (int r = 0; r < 2; ++r) {
            int slot = s * 2 + r;
            uint i = (uint)(r * 64 + lane);
            if (i < sc) {
                uint idx = spillIdx[w][s][i];
                float4 p = pts4[idx];
                uint key = fkey(dist2f(qw, p));
                sp[slot] = ((u64)key << 32) | idx;
                uint rel = key - kbase;
                uint b = (key < kbase) ? 0u : (rel >> 16);
                if (b > 255u) b = 255u;
                bn[slot] = b;
                atomicAdd(&hist[w][b], 1u);
            } else { sp[slot] = ~0ull; bn[slot] = 0xffffffffu; }
        }
    }

    // per-wave scan of 256 bins (4/lane): crossing bin B, count strictly below
    uint h0 = hist[w][lane * 4 + 0], h1 = hist[w][lane * 4 + 1];
    uint h2 = hist[w][lane * 4 + 2], h3 = hist[w][lane * 4 + 3];
    uint s4 = h0 + h1 + h2 + h3;
    uint x = s4;
    for (int off = 1; off < 64; off <<= 1) {
        uint y = __shfl_up(x, off);
        if (lane >= off) x += y;
    }
    uint excl = x - s4;
    bool cross = (excl < KNN) && (excl + s4 >= KNN);
    u64 mkc = __ballot(cross);
    uint Bl = 0, nbl = 0;
    if (cross) {
        uint cum = excl;
        if (cum + h0 >= KNN)                { Bl = lane * 4u + 0; nbl = cum; }
        else if (cum + h0 + h1 >= KNN)      { Bl = lane * 4u + 1; nbl = cum + h0; }
        else if (cum + h0 + h1 + h2 >= KNN) { Bl = lane * 4u + 2; nbl = cum + h0 + h1; }
        else                                { Bl = lane * 4u + 3; nbl = cum + h0 + h1 + h2; }
    }
    uint B, nbelow;
    if (mkc == 0ull) { B = 255u; nbelow = 0u; }
    else {
        int src = __ffsll((unsigned long long)mkc) - 1;
        B = __shfl(Bl, src);
        nbelow = __shfl(nbl, src);
    }

    // direct-write bins < B (canonical slot order -> deterministic)
    uint obase = (uint)(qbase + w) * KNN;
    uint dpos = 0;
#pragma unroll
    for (int slot = 0; slot < 8; ++slot) {
        bool dw = (bn[slot] < B);
        u64 mk2 = __ballot(dw);
        if (mk2) {
            uint pos = dpos + (uint)__popcll(mk2 & lmlt);
            if (dw) knn_idx[obase + pos] = (uint)sp[slot];
            dpos += (uint)__popcll(mk2);
        }
        if (bn[slot] != B) sp[slot] = ~0ull;   // keep only bin-B items
    }

    // exact (key,idx)-ordered select of the remaining `need`
    uint need = KNN - nbelow;
    for (uint itx = 0; itx < need; ++itx) {
        u64 m = sp[0];
#pragma unroll
        for (int s2 = 1; s2 < 8; ++s2) if (sp[s2] < m) m = sp[s2];
        for (int off = 32; off >= 1; off >>= 1) {
            u64 o = __shfl_xor(m, off);
            if (o < m) m = o;
        }
#pragma unroll
        for (int s2 = 0; s2 < 8; ++s2) if (sp[s2] == m) sp[s2] = ~0ull;
        if (lane == 0) knn_idx[obase + nbelow + itx] = (uint)m;
    }
}

// ---------------------------------------------------------------------------
// wave-per-query: softmax weights + weighted maxpool over g + point branch.
// Writes F row-major: F[n][c], c in [0,256)  (coalesced).
__launch_bounds__(256)
__global__ void k_surpc(const float4* __restrict__ pts4, const uint* __restrict__ knn_idx,
                        const float* __restrict__ g, const float* __restrict__ Wpc,
                        const float* __restrict__ bpc, float* __restrict__ F) {
    int t = threadIdx.x;
    int w = t >> 6;
    int lane = t & 63;
    int q = blockIdx.x * 4 + w;
    int k = lane & 31;
    uint j = knn_idx[q * KNN + k];
    float4 qp = pts4[q];
    float4 pj = pts4[j];
    float dx = qp.x - pj.x, dy = qp.y - pj.y, dz = qp.z - pj.z;
    float dist = sqrtf(fmaf(dx, dx, fmaf(dy, dy, dz * dz)));
    float dmin = dist;
    for (int off = 16; off >= 1; off >>= 1) dmin = fminf(dmin, __shfl_xor(dmin, off));
    float e = expf(dmin - dist);
    float S = e;
    for (int off = 16; off >= 1; off >>= 1) S += __shfl_xor(S, off);

    int d0 = lane * 2;
    float m0 = -INFINITY, m1 = -INFINITY;
#pragma unroll 8
    for (int kk = 0; kk < 32; ++kk) {
        float ek = __shfl(e, kk);
        int jk = __shfl((int)j, kk);
        float2 gv = *(const float2*)&g[(uint)jk * 128 + d0];
        m0 = fmaxf(m0, ek * gv.x);
        m1 = fmaxf(m1, ek * gv.y);
    }
    float inv = 1.0f / S;
    float s0 = m0 * inv, s1 = m1 * inv;

    float p0 = bpc[d0 + 0];
    p0 = fmaf(Wpc[(d0 + 0) * 3 + 0], qp.x, p0);
    p0 = fmaf(Wpc[(d0 + 0) * 3 + 1], qp.y, p0);
    p0 = fmaf(Wpc[(d0 + 0) * 3 + 2], qp.z, p0);
    float p1 = bpc[d0 + 1];
    p1 = fmaf(Wpc[(d0 + 1) * 3 + 0], qp.x, p1);
    p1 = fmaf(Wpc[(d0 + 1) * 3 + 1], qp.y, p1);
    p1 = fmaf(Wpc[(d0 + 1) * 3 + 2], qp.z, p1);

    *(float2*)&F[q * 256 + d0] = make_float2(s0, s1);
    *(float2*)&F[q * 256 + 128 + d0] = make_float2(p0, p1);
}

// ---------------------------------------------------------------------------
// out[d][n] = sum_c Wf[d][c] * F[n][c] + bf[d]
__launch_bounds__(256)
__global__ void k_final(const float* __restrict__ F, const float* __restrict__ Wf,
                        const float* __restrict__ bf, float* __restrict__ out) {
    __shared__ float Fs[256 * 34];     // [k][n], pad 34 keeps 8B align + banks spread
    __shared__ float wfs[32 * 132];    // [kk][d] padded
    int t = threadIdx.x;
    int tn = t & 15;
    int td = t >> 4;
    int n0 = blockIdx.x * 32;
    int d0 = td * 8;

    for (int i = t; i < 32 * 256; i += 256) {
        int nn = i >> 8, kk = i & 255;
        Fs[kk * 34 + nn] = F[(n0 + nn) * 256 + kk];
    }

    float acc[2][8];
#pragma unroll
    for (int a = 0; a < 2; ++a)
#pragma unroll
        for (int b = 0; b < 8; ++b) acc[a][b] = 0.f;

    for (int kc = 0; kc < 8; ++kc) {
        __syncthreads();
        for (int i = t; i < 32 * 128; i += 256) {
            int kk = i & 31, d = i >> 5;
            wfs[kk * 132 + d] = Wf[d * 256 + kc * 32 + kk];
        }
        __syncthreads();
#pragma unroll 4
        for (int kk = 0; kk < 32; ++kk) {
            int k = kc * 32 + kk;
            float2 f = *(const float2*)&Fs[k * 34 + tn * 2];
            const float* wr = &wfs[kk * 132 + d0];
            float4 wa = *(const float4*)wr;
            float4 wb = *(const float4*)(wr + 4);
            acc[0][0] = fmaf(f.x, wa.x, acc[0][0]); acc[1][0] = fmaf(f.y, wa.x, acc[1][0]);
            acc[0][1] = fmaf(f.x, wa.y, acc[0][1]); acc[1][1] = fmaf(f.y, wa.y, acc[1][1]);
            acc[0][2] = fmaf(f.x, wa.z, acc[0][2]); acc[1][2] = fmaf(f.y, wa.z, acc[1][2]);
            acc[0][3] = fmaf(f.x, wa.w, acc[0][3]); acc[1][3] = fmaf(f.y, wa.w, acc[1][3]);
            acc[0][4] = fmaf(f.x, wb.x, acc[0][4]); acc[1][4] = fmaf(f.y, wb.x, acc[1][4]);
            acc[0][5] = fmaf(f.x, wb.y, acc[0][5]); acc[1][5] = fmaf(f.y, wb.y, acc[1][5]);
            acc[0][6] = fmaf(f.x, wb.z, acc[0][6]); acc[1][6] = fmaf(f.y, wb.z, acc[1][6]);
            acc[0][7] = fmaf(f.x, wb.w, acc[0][7]); acc[1][7] = fmaf(f.y, wb.w, acc[1][7]);
        }
    }
#pragma unroll
    for (int dd = 0; dd < 8; ++dd) {
        int d = d0 + dd;
        float b = bf[d];
        *(float2*)&out[d * NPTS + n0 + tn * 2] = make_float2(acc[0][dd] + b, acc[1][dd] + b);
    }
}

// ---------------------------------------------------------------------------
extern "C" void kernel_launch(void* const* d_in, const int* in_sizes, int n_in,
                              void* d_out, int out_size, void* d_ws, size_t ws_size,
                              hipStream_t stream) {
    const float* img_feat = (const float*)d_in[0];
    const float* cloud    = (const float*)d_in[1];
    const float* W1  = (const float*)d_in[2];
    const float* b1  = (const float*)d_in[3];
    const float* W2  = (const float*)d_in[4];
    const float* b2  = (const float*)d_in[5];
    const float* Wp1 = (const float*)d_in[6];
    const float* bp1 = (const float*)d_in[7];
    const float* Wp2 = (const float*)d_in[8];
    const float* bp2 = (const float*)d_in[9];
    const float* Wf  = (const float*)d_in[10];
    const float* bf  = (const float*)d_in[11];
    float* out = (float*)d_out;

    char* ws = (char*)d_ws;
    float4* pts4 = (float4*)(ws + OFF_PTS4);
    float* Wc  = (float*)(ws + OFF_WC);
    float* bc  = (float*)(ws + OFF_BC);
    float* Wpc = (float*)(ws + OFF_WPC);
    float* bpc = (float*)(ws + OFF_BPC);
    float* g   = (float*)(ws + OFF_G);
    uint* knn_idx = (uint*)(ws + OFF_IDX);
    float* F   = (float*)(ws + OFF_F);

    k_prep_combine<<<51, 256, 0, stream>>>(cloud, pts4, W1, b1, W2, b2,
                                           Wp1, bp1, Wp2, bp2, Wc, bc, Wpc, bpc);
    k_knn<<<NPTS / 4, 256, 0, stream>>>(pts4, knn_idx);
    k_gfeat<<<NPTS / 16, 256, 0, stream>>>(img_feat, Wc, bc, g);
    k_surpc<<<NPTS / 4, 256, 0, stream>>>(pts4, knn_idx, g, Wpc, bpc, F);
    k_final<<<NPTS / 32, 256, 0, stream>>>(F, Wf, bf, out);
}

// Round 4
// 94.605 us; speedup vs baseline: 2.9575x; 1.2243x over previous
//
#include <hip/hip_runtime.h>
#include <math.h>

#define NPTS 8192
#define KNN 32

typedef unsigned int uint;
typedef unsigned long long u64;

// ---- workspace layout (bytes) ----
#define OFF_PTS4 0                      // float4[N]            131072
#define OFF_WC   131072                 // float[128*32]        16384
#define OFF_BC   147456                 // float[128]           512
#define OFF_WPC  147968                 // float[128*3]         1536
#define OFF_BPC  149504                 // float[128]           512
#define OFF_G    150016                 // float[N*128]         4194304
#define OFF_IDX  4344320                // uint[N*32]           1048576
#define OFF_F    5392896                // float[N*256] row-major 8388608

// Shared distance arithmetic: MUST be bit-identical in every pass.
__device__ __forceinline__ float dist2f(const float4 q, const float4 p) {
    float dot = fmaf(q.x, p.x, fmaf(q.y, p.y, q.z * p.z));
    return (q.w + p.w) - 2.0f * dot;
}
__device__ __forceinline__ uint fkey(float d) {
    uint bits = __float_as_uint(d);
    return bits ^ (0x80000000u | (uint)((int)bits >> 31));  // monotone sortable
}
__device__ __forceinline__ float finv(uint key) {
    uint bits = (key & 0x80000000u) ? (key ^ 0x80000000u) : ~key;
    return __uint_as_float(bits);
}
// popcount of mask bits strictly below this lane (2 VALU)
__device__ __forceinline__ uint mbcnt64(u64 m) {
    uint lo = __builtin_amdgcn_mbcnt_lo((uint)m, 0u);
    return __builtin_amdgcn_mbcnt_hi((uint)(m >> 32), lo);
}

// ---------------------------------------------------------------------------
// Fused: blocks 0..31 build pts4; blocks 32..50 collapse the MLP chains.
__launch_bounds__(256)
__global__ void k_prep_combine(const float* __restrict__ cloud, float4* __restrict__ pts4,
                               const float* __restrict__ W1, const float* __restrict__ b1,
                               const float* __restrict__ W2, const float* __restrict__ b2,
                               const float* __restrict__ Wp1, const float* __restrict__ bp1,
                               const float* __restrict__ Wp2, const float* __restrict__ bp2,
                               float* __restrict__ Wc, float* __restrict__ bc,
                               float* __restrict__ Wpc, float* __restrict__ bpc) {
    int bid = blockIdx.x;
    int t = threadIdx.x;
    if (bid < 32) {
        int n = bid * 256 + t;
        float x = cloud[n * 3 + 0], y = cloud[n * 3 + 1], z = cloud[n * 3 + 2];
        float sq = fmaf(x, x, fmaf(y, y, z * z));
        pts4[n] = make_float4(x, y, z, sq);
        return;
    }
    int id = (bid - 32) * 256 + t;
    if (id < 4096) {                 // Wc[d][c] = sum_o W2[d][o] W1[o][c]
        int d = id >> 5, c = id & 31;
        float a0 = 0.f, a1 = 0.f;
        for (int o = 0; o < 64; o += 2) {
            a0 = fmaf(W2[d * 64 + o], W1[o * 32 + c], a0);
            a1 = fmaf(W2[d * 64 + o + 1], W1[(o + 1) * 32 + c], a1);
        }
        Wc[id] = a0 + a1;
    } else if (id < 4224) {          // bc[d]
        int d = id - 4096;
        float a = b2[d];
        for (int o = 0; o < 64; ++o) a = fmaf(W2[d * 64 + o], b1[o], a);
        bc[d] = a;
    } else if (id < 4608) {          // Wpc[d][c]
        int i = id - 4224, d = i / 3, c = i - d * 3;
        float a = 0.f;
        for (int o = 0; o < 64; ++o) a = fmaf(Wp2[d * 64 + o], Wp1[o * 3 + c], a);
        Wpc[i] = a;
    } else if (id < 4736) {          // bpc[d]
        int d = id - 4608;
        float a = bp2[d];
        for (int o = 0; o < 64; ++o) a = fmaf(Wp2[d * 64 + o], bp1[o], a);
        bpc[d] = a;
    }
}

// ---------------------------------------------------------------------------
// g[n][d] = sum_c Wc[d][c] * feats[n][c] + bc[d]   (feats[n][c] = img_feat[c*N+n])
__launch_bounds__(256)
__global__ void k_gfeat(const float* __restrict__ img_feat, const float* __restrict__ Wc,
                        const float* __restrict__ bc, float* __restrict__ g) {
    __shared__ float wcs[128 * 33];
    __shared__ float bcs[128];
    __shared__ float ft[32][16];
    int t = threadIdx.x;
    int n0 = blockIdx.x * 16;
    for (int i = t; i < 128 * 32; i += 256) { int dd = i >> 5, cc = i & 31; wcs[dd * 33 + cc] = Wc[i]; }
    if (t < 128) bcs[t] = bc[t];
    for (int i = t; i < 32 * 16; i += 256) { int cc = i >> 4, nn = i & 15; ft[cc][nn] = img_feat[cc * NPTS + n0 + nn]; }
    __syncthreads();
    int d = t & 127;
    int ng = t >> 7;
    for (int nl = ng * 8; nl < ng * 8 + 8; ++nl) {
        float a = bcs[d];
#pragma unroll
        for (int c = 0; c < 32; ++c) a = fmaf(wcs[d * 33 + c], ft[c][nl], a);
        g[(n0 + nl) * 128 + d] = a;
    }
}

// ---------------------------------------------------------------------------
// Exact KNN v4: shuffle-free, atomic-free select via ballot bit-radix.
// 4 queries / block (4 waves). Prepass: wave w thresholds its own query.
// Sweep: wave w sweeps candidate quarter w for all 4 queries (ballot-compacted
// spill, deterministic). Refine: wave w selects exact top-32 for query w via
// ballot radix-select on (key, idx) — no LDS histogram, no shuffle chains.
#define CAPSEG 96
__launch_bounds__(256)
__global__ void k_knn(const float4* __restrict__ pts4, uint* __restrict__ knn_idx) {
    __shared__ uint spillIdx[4][4][CAPSEG];   // [q][seg(=sweep wave)][slot]  6 KB
    __shared__ uint segcnt[4][4];             // [q][seg]
    __shared__ float Tsh[4];

    int t = threadIdx.x, w = t >> 6, lane = t & 63;
    int qbase = blockIdx.x * 4;
    float4 q0 = pts4[qbase + 0], q1 = pts4[qbase + 1];
    float4 q2 = pts4[qbase + 2], q3 = pts4[qbase + 3];
    float4 qw = (w == 0) ? q0 : (w == 1) ? q1 : (w == 2) ? q2 : q3;

    // ---- prepass: per-lane min over samples 0..2047, OWN query only ----
    float mn = 3.4e38f;
    {
        float4 pp = pts4[lane];
        for (int s = 0; s < 32; ++s) {
            float4 pnx;
            if (s < 31) pnx = pts4[lane + ((s + 1) << 6)];
            mn = fminf(mn, dist2f(qw, pp));
            pp = pnx;
        }
    }
    // exact 32nd-smallest of the 64 lane minima: ballot bit-radix (no shuffles)
    {
        uint kmn = fkey(mn);
        uint P = 0u;
        for (int b = 31; b >= 0; --b) {
            uint cand = P | (1u << b);
            u64 m = __ballot(kmn < cand);
            if ((uint)__popcll(m) < 32u) P = cand;
        }
        if (lane == 0) Tsh[w] = finv(P);
    }
    __syncthreads();
    float T0 = Tsh[0], T1 = Tsh[1], T2 = Tsh[2], T3 = Tsh[3];

    // ---- sweep: wave w covers [w*2048,(w+1)*2048) for all 4 queries ----
    uint c0 = 0, c1 = 0, c2 = 0, c3 = 0;
    int cbase = (w << 11) + lane;

#define SPQ(Q, TQ, CQ) { float d2_ = dist2f(q##Q, p); bool in_ = d2_ <= TQ; \
    u64 mk_ = __ballot(in_); \
    uint pos_ = CQ + mbcnt64(mk_); \
    if (in_ && pos_ < CAPSEG) spillIdx[Q][w][pos_] = cidx; \
    CQ += (uint)__popcll(mk_); }

    {
        float4 p = pts4[cbase];
        for (int it = 0; it < 32; ++it) {
            float4 pn;
            if (it < 31) pn = pts4[cbase + ((it + 1) << 6)];
            uint cidx = (uint)(cbase + (it << 6));
            SPQ(0, T0, c0)
            SPQ(1, T1, c1)
            SPQ(2, T2, c2)
            SPQ(3, T3, c3)
            p = pn;
        }
    }
    if (lane == 0) {
        segcnt[0][w] = c0; segcnt[1][w] = c1; segcnt[2][w] = c2; segcnt[3][w] = c3;
    }
    __syncthreads();

    // ---- refine: wave w selects exact top-32 for query qbase+w ----
    uint kk[8], id[8];
#pragma unroll
    for (int s = 0; s < 4; ++s) {
        uint sc = segcnt[w][s];
        if (sc > CAPSEG) sc = CAPSEG;
#pragma unroll
        for (int r = 0; r < 2; ++r) {
            int slot = s * 2 + r;
            uint i = (uint)(r * 64 + lane);
            if (i < sc) {
                uint idx = spillIdx[w][s][i];
                float4 pz = pts4[idx];
                kk[slot] = fkey(dist2f(qw, pz));
                id[slot] = idx;
            } else { kk[slot] = 0xFFFFFFFFu; id[slot] = 0xFFFFFFFFu; }
        }
    }

    // stage 1: Kc = key of the 32nd-smallest candidate (with multiplicity)
    uint Kc = 0u;
    for (int b = 31; b >= 0; --b) {
        uint cand = Kc | (1u << b);
        uint cnt = 0;
#pragma unroll
        for (int s = 0; s < 8; ++s) cnt += (uint)__popcll(__ballot(kk[s] < cand));
        if (cnt < 32u) Kc = cand;
    }
    uint nlt = 0, ntie = 0;
#pragma unroll
    for (int s = 0; s < 8; ++s) {
        nlt  += (uint)__popcll(__ballot(kk[s] < Kc));
        ntie += (uint)__popcll(__ballot(kk[s] == Kc));
    }
    uint need = 32u - nlt;
    uint icut = 0xFFFFFFFFu;
    if (ntie != need) {
        // tie-break by index: need-th smallest idx among ties (ids unique)
        uint Q2 = 0u;
        for (int b = 12; b >= 0; --b) {
            uint cand = Q2 | (1u << b);
            uint cnt = 0;
#pragma unroll
            for (int s = 0; s < 8; ++s)
                cnt += (uint)__popcll(__ballot(kk[s] == Kc && id[s] < cand));
            if (cnt < need) Q2 = cand;
        }
        icut = Q2;
    }

    // ballot-compacted direct write of exactly 32 indices (order irrelevant
    // downstream: gather/softmax/max are permutation-invariant)
    uint obase = (uint)(qbase + w) * KNN;
    uint dpos = 0;
#pragma unroll
    for (int s = 0; s < 8; ++s) {
        bool acc = (kk[s] < Kc) || (kk[s] == Kc && id[s] <= icut);
        u64 mk = __ballot(acc);
        uint pos = dpos + mbcnt64(mk);
        if (acc) knn_idx[obase + pos] = id[s];
        dpos += (uint)__popcll(mk);
    }
}

// ---------------------------------------------------------------------------
// wave-per-query: softmax weights + weighted maxpool over g + point branch.
// Writes F row-major: F[n][c], c in [0,256)  (coalesced).
__launch_bounds__(256)
__global__ void k_surpc(const float4* __restrict__ pts4, const uint* __restrict__ knn_idx,
                        const float* __restrict__ g, const float* __restrict__ Wpc,
                        const float* __restrict__ bpc, float* __restrict__ F) {
    int t = threadIdx.x;
    int w = t >> 6;
    int lane = t & 63;
    int q = blockIdx.x * 4 + w;
    int k = lane & 31;
    uint j = knn_idx[q * KNN + k];
    float4 qp = pts4[q];
    float4 pj = pts4[j];
    float dx = qp.x - pj.x, dy = qp.y - pj.y, dz = qp.z - pj.z;
    float dist = sqrtf(fmaf(dx, dx, fmaf(dy, dy, dz * dz)));
    float dmin = dist;
    for (int off = 16; off >= 1; off >>= 1) dmin = fminf(dmin, __shfl_xor(dmin, off));
    float e = expf(dmin - dist);
    float S = e;
    for (int off = 16; off >= 1; off >>= 1) S += __shfl_xor(S, off);

    int d0 = lane * 2;
    float m0 = -INFINITY, m1 = -INFINITY;
#pragma unroll 8
    for (int kk = 0; kk < 32; ++kk) {
        float ek = __shfl(e, kk);
        int jk = __shfl((int)j, kk);
        float2 gv = *(const float2*)&g[(uint)jk * 128 + d0];
        m0 = fmaxf(m0, ek * gv.x);
        m1 = fmaxf(m1, ek * gv.y);
    }
    float inv = 1.0f / S;
    float s0 = m0 * inv, s1 = m1 * inv;

    float p0 = bpc[d0 + 0];
    p0 = fmaf(Wpc[(d0 + 0) * 3 + 0], qp.x, p0);
    p0 = fmaf(Wpc[(d0 + 0) * 3 + 1], qp.y, p0);
    p0 = fmaf(Wpc[(d0 + 0) * 3 + 2], qp.z, p0);
    float p1 = bpc[d0 + 1];
    p1 = fmaf(Wpc[(d0 + 1) * 3 + 0], qp.x, p1);
    p1 = fmaf(Wpc[(d0 + 1) * 3 + 1], qp.y, p1);
    p1 = fmaf(Wpc[(d0 + 1) * 3 + 2], qp.z, p1);

    *(float2*)&F[q * 256 + d0] = make_float2(s0, s1);
    *(float2*)&F[q * 256 + 128 + d0] = make_float2(p0, p1);
}

// ---------------------------------------------------------------------------
// out[d][n] = sum_c Wf[d][c] * F[n][c] + bf[d]
__launch_bounds__(256)
__global__ void k_final(const float* __restrict__ F, const float* __restrict__ Wf,
                        const float* __restrict__ bf, float* __restrict__ out) {
    __shared__ float Fs[256 * 34];     // [k][n], pad 34 keeps 8B align + banks spread
    __shared__ float wfs[32 * 132];    // [kk][d] padded
    int t = threadIdx.x;
    int tn = t & 15;
    int td = t >> 4;
    int n0 = blockIdx.x * 32;
    int d0 = td * 8;

    for (int i = t; i < 32 * 256; i += 256) {
        int nn = i >> 8, kk = i & 255;
        Fs[kk * 34 + nn] = F[(n0 + nn) * 256 + kk];
    }

    float acc[2][8];
#pragma unroll
    for (int a = 0; a < 2; ++a)
#pragma unroll
        for (int b = 0; b < 8; ++b) acc[a][b] = 0.f;

    for (int kc = 0; kc < 8; ++kc) {
        __syncthreads();
        for (int i = t; i < 32 * 128; i += 256) {
            int kk = i & 31, d = i >> 5;
            wfs[kk * 132 + d] = Wf[d * 256 + kc * 32 + kk];
        }
        __syncthreads();
#pragma unroll 4
        for (int kk = 0; kk < 32; ++kk) {
            int k = kc * 32 + kk;
            float2 f = *(const float2*)&Fs[k * 34 + tn * 2];
            const float* wr = &wfs[kk * 132 + d0];
            float4 wa = *(const float4*)wr;
            float4 wb = *(const float4*)(wr + 4);
            acc[0][0] = fmaf(f.x, wa.x, acc[0][0]); acc[1][0] = fmaf(f.y, wa.x, acc[1][0]);
            acc[0][1] = fmaf(f.x, wa.y, acc[0][1]); acc[1][1] = fmaf(f.y, wa.y, acc[1][1]);
            acc[0][2] = fmaf(f.x, wa.z, acc[0][2]); acc[1][2] = fmaf(f.y, wa.z, acc[1][2]);
            acc[0][3] = fmaf(f.x, wa.w, acc[0][3]); acc[1][3] = fmaf(f.y, wa.w, acc[1][3]);
            acc[0][4] = fmaf(f.x, wb.x, acc[0][4]); acc[1][4] = fmaf(f.y, wb.x, acc[1][4]);
            acc[0][5] = fmaf(f.x, wb.y, acc[0][5]); acc[1][5] = fmaf(f.y, wb.y, acc[1][5]);
            acc[0][6] = fmaf(f.x, wb.z, acc[0][6]); acc[1][6] = fmaf(f.y, wb.z, acc[1][6]);
            acc[0][7] = fmaf(f.x, wb.w, acc[0][7]); acc[1][7] = fmaf(f.y, wb.w, acc[1][7]);
        }
    }
#pragma unroll
    for (int dd = 0; dd < 8; ++dd) {
        int d = d0 + dd;
        float b = bf[d];
        *(float2*)&out[d * NPTS + n0 + tn * 2] = make_float2(acc[0][dd] + b, acc[1][dd] + b);
    }
}

// ---------------------------------------------------------------------------
extern "C" void kernel_launch(void* const* d_in, const int* in_sizes, int n_in,
                              void* d_out, int out_size, void* d_ws, size_t ws_size,
                              hipStream_t stream) {
    const float* img_feat = (const float*)d_in[0];
    const float* cloud    = (const float*)d_in[1];
    const float* W1  = (const float*)d_in[2];
    const float* b1  = (const float*)d_in[3];
    const float* W2  = (const float*)d_in[4];
    const float* b2  = (const float*)d_in[5];
    const float* Wp1 = (const float*)d_in[6];
    const float* bp1 = (const float*)d_in[7];
    const float* Wp2 = (const float*)d_in[8];
    const float* bp2 = (const float*)d_in[9];
    const float* Wf  = (const float*)d_in[10];
    const float* bf  = (const float*)d_in[11];
    float* out = (float*)d_out;

    char* ws = (char*)d_ws;
    float4* pts4 = (float4*)(ws + OFF_PTS4);
    float* Wc  = (float*)(ws + OFF_WC);
    float* bc  = (float*)(ws + OFF_BC);
    float* Wpc = (float*)(ws + OFF_WPC);
    float* bpc = (float*)(ws + OFF_BPC);
    float* g   = (float*)(ws + OFF_G);
    uint* knn_idx = (uint*)(ws + OFF_IDX);
    float* F   = (float*)(ws + OFF_F);

    k_prep_combine<<<51, 256, 0, stream>>>(cloud, pts4, W1, b1, W2, b2,
                                           Wp1, bp1, Wp2, bp2, Wc, bc, Wpc, bpc);
    k_knn<<<NPTS / 4, 256, 0, stream>>>(pts4, knn_idx);
    k_gfeat<<<NPTS / 16, 256, 0, stream>>>(img_feat, Wc, bc, g);
    k_surpc<<<NPTS / 4, 256, 0, stream>>>(pts4, knn_idx, g, Wpc, bpc, F);
    k_final<<<NPTS / 32, 256, 0, stream>>>(F, Wf, bf, out);
}

// Round 5
// 85.003 us; speedup vs baseline: 3.2916x; 1.1130x over previous
//
#include <hip/hip_runtime.h>
#include <math.h>

#define NPTS 8192
#define KNN 32

typedef unsigned int uint;
typedef unsigned long long u64;
typedef float v2f __attribute__((ext_vector_type(2)));

// packed fp32 fma (v_pk_fma_f32 on gfx90a+); falls back to 2x scalar IEEE fma
#if __has_builtin(__builtin_elementwise_fma)
__device__ __forceinline__ v2f fma2(v2f a, v2f b, v2f c) {
    return __builtin_elementwise_fma(a, b, c);
}
#else
__device__ __forceinline__ v2f fma2(v2f a, v2f b, v2f c) {
    v2f r; r.x = fmaf(a.x, b.x, c.x); r.y = fmaf(a.y, b.y, c.y); return r;
}
#endif
__device__ __forceinline__ v2f mk2(float a, float b) { v2f r; r.x = a; r.y = b; return r; }

// ---- workspace layout (bytes) ----
#define OFF_PTS4 0                      // float4[N]            131072
#define OFF_WC   131072                 // float[128*32]        16384
#define OFF_BC   147456                 // float[128]           512
#define OFF_WPC  147968                 // float[128*3]         1536
#define OFF_BPC  149504                 // float[128]           512
#define OFF_G    150016                 // float[N*128]         4194304
#define OFF_F    5392896                // float[N*256] row-major 8388608

__device__ __forceinline__ uint fkey(float d) {
    uint bits = __float_as_uint(d);
    return bits ^ (0x80000000u | (uint)((int)bits >> 31));  // monotone sortable
}
__device__ __forceinline__ float finv(uint key) {
    uint bits = (key & 0x80000000u) ? (key ^ 0x80000000u) : ~key;
    return __uint_as_float(bits);
}
__device__ __forceinline__ uint mbcnt64(u64 m) {
    uint lo = __builtin_amdgcn_mbcnt_lo((uint)m, 0u);
    return __builtin_amdgcn_mbcnt_hi((uint)(m >> 32), lo);
}

// ---------------------------------------------------------------------------
// Fused: blocks 0..31 build pts4; blocks 32..50 collapse the MLP chains.
__launch_bounds__(256)
__global__ void k_prep_combine(const float* __restrict__ cloud, float4* __restrict__ pts4,
                               const float* __restrict__ W1, const float* __restrict__ b1,
                               const float* __restrict__ W2, const float* __restrict__ b2,
                               const float* __restrict__ Wp1, const float* __restrict__ bp1,
                               const float* __restrict__ Wp2, const float* __restrict__ bp2,
                               float* __restrict__ Wc, float* __restrict__ bc,
                               float* __restrict__ Wpc, float* __restrict__ bpc) {
    int bid = blockIdx.x;
    int t = threadIdx.x;
    if (bid < 32) {
        int n = bid * 256 + t;
        float x = cloud[n * 3 + 0], y = cloud[n * 3 + 1], z = cloud[n * 3 + 2];
        float sq = fmaf(x, x, fmaf(y, y, z * z));
        pts4[n] = make_float4(x, y, z, sq);
        return;
    }
    int id = (bid - 32) * 256 + t;
    if (id < 4096) {                 // Wc[d][c] = sum_o W2[d][o] W1[o][c]
        int d = id >> 5, c = id & 31;
        float a0 = 0.f, a1 = 0.f;
        for (int o = 0; o < 64; o += 2) {
            a0 = fmaf(W2[d * 64 + o], W1[o * 32 + c], a0);
            a1 = fmaf(W2[d * 64 + o + 1], W1[(o + 1) * 32 + c], a1);
        }
        Wc[id] = a0 + a1;
    } else if (id < 4224) {          // bc[d]
        int d = id - 4096;
        float a = b2[d];
        for (int o = 0; o < 64; ++o) a = fmaf(W2[d * 64 + o], b1[o], a);
        bc[d] = a;
    } else if (id < 4608) {          // Wpc[d][c]
        int i = id - 4224, d = i / 3, c = i - d * 3;
        float a = 0.f;
        for (int o = 0; o < 64; ++o) a = fmaf(Wp2[d * 64 + o], Wp1[o * 3 + c], a);
        Wpc[i] = a;
    } else if (id < 4736) {          // bpc[d]
        int d = id - 4608;
        float a = bp2[d];
        for (int o = 0; o < 64; ++o) a = fmaf(Wp2[d * 64 + o], bp1[o], a);
        bpc[d] = a;
    }
}

// ---------------------------------------------------------------------------
// g[n][d] = sum_c Wc[d][c] * feats[n][c] + bc[d]   (feats[n][c] = img_feat[c*N+n])
__launch_bounds__(256)
__global__ void k_gfeat(const float* __restrict__ img_feat, const float* __restrict__ Wc,
                        const float* __restrict__ bc, float* __restrict__ g) {
    __shared__ float wcs[128 * 33];
    __shared__ float bcs[128];
    __shared__ float ft[32][16];
    int t = threadIdx.x;
    int n0 = blockIdx.x * 16;
    for (int i = t; i < 128 * 32; i += 256) { int dd = i >> 5, cc = i & 31; wcs[dd * 33 + cc] = Wc[i]; }
    if (t < 128) bcs[t] = bc[t];
    for (int i = t; i < 32 * 16; i += 256) { int cc = i >> 4, nn = i & 15; ft[cc][nn] = img_feat[cc * NPTS + n0 + nn]; }
    __syncthreads();
    int d = t & 127;
    int ng = t >> 7;
    for (int nl = ng * 8; nl < ng * 8 + 8; ++nl) {
        float a = bcs[d];
#pragma unroll
        for (int c = 0; c < 32; ++c) a = fmaf(wcs[d * 33 + c], ft[c][nl], a);
        g[(n0 + nl) * 128 + d] = a;
    }
}

// ---------------------------------------------------------------------------
// Exact KNN + fused surround/point branch. 4 queries / block (4 waves).
// Prepass: wave w thresholds its own query (ballot bit-radix, no shuffles).
// Sweep: wave w sweeps candidate quarter w for all 4 queries with PACKED fp32
//   distance math (v_pk_fma_f32), ballot-compacted spill (deterministic).
// Refine: wave w compacts spill segments, ballot radix-selects exact top-32
//   (tie-break by index), writes them to LDS.
// Fused epilogue: same wave computes softmax weights + weighted maxpool over
//   g + the point branch, writing F[n][256] directly (no knn_idx round-trip).
#define CAPSEG 96
__launch_bounds__(256)
__global__ void k_knn(const float4* __restrict__ pts4, const float* __restrict__ g,
                      const float* __restrict__ Wpc, const float* __restrict__ bpc,
                      float* __restrict__ F) {
    __shared__ uint spillIdx[4][4][CAPSEG];   // [q][seg(=sweep wave)][slot]  6 KB
    __shared__ uint segcnt[4][4];             // [q][seg]
    __shared__ float Tsh[4];
    __shared__ uint2 selEJ[4][32];            // per query: (.x = e bits, .y = idx)

    int t = threadIdx.x, w = t >> 6, lane = t & 63;
    int qbase = blockIdx.x * 4;
    float4 qA = pts4[qbase + 0], qB = pts4[qbase + 1];
    float4 qC = pts4[qbase + 2], qD = pts4[qbase + 3];
    float4 qq = (w == 0) ? qA : (w == 1) ? qB : (w == 2) ? qC : qD;

    // packed per-query constants: d2 = fma(-2qx,px, fma(-2qy,py, fma(-2qz,pz, qw+pw)))
    v2f m2xAB = mk2(-2.f * qA.x, -2.f * qB.x), m2xCD = mk2(-2.f * qC.x, -2.f * qD.x);
    v2f m2yAB = mk2(-2.f * qA.y, -2.f * qB.y), m2yCD = mk2(-2.f * qC.y, -2.f * qD.y);
    v2f m2zAB = mk2(-2.f * qA.z, -2.f * qB.z), m2zCD = mk2(-2.f * qC.z, -2.f * qD.z);
    v2f qwAB = mk2(qA.w, qB.w), qwCD = mk2(qC.w, qD.w);
    float m2x = -2.f * qq.x, m2y = -2.f * qq.y, m2z = -2.f * qq.z, qw4 = qq.w;

    // ---- prepass: per-lane min over samples 0..2047, OWN query only ----
    float mn = 3.4e38f;
    {
        float4 pp = pts4[lane];
        for (int s = 0; s < 32; ++s) {
            float4 pnx;
            if (s < 31) pnx = pts4[lane + ((s + 1) << 6)];
            float d2 = fmaf(m2x, pp.x, fmaf(m2y, pp.y, fmaf(m2z, pp.z, qw4 + pp.w)));
            mn = fminf(mn, d2);
            pp = pnx;
        }
    }
    // exact 32nd-smallest of the 64 lane minima (bit-radix on ballots).
    // seed bit31: keys of (at worst one slightly-negative self-d2) < 0x80000000
    // number far fewer than 32, so invariant count(<P)<32 holds at the seed.
    {
        uint kmn = fkey(mn);
        uint P = 0x80000000u;
        for (int b = 30; b >= 0; --b) {
            uint cand = P | (1u << b);
            if ((uint)__popcll(__ballot(kmn < cand)) < 32u) P = cand;
        }
        if (lane == 0) Tsh[w] = finv(P);
    }
    __syncthreads();
    float T0 = Tsh[0], T1 = Tsh[1], T2 = Tsh[2], T3 = Tsh[3];

    // ---- sweep: wave w covers [w*2048,(w+1)*2048) for all 4 queries ----
    uint c0 = 0, c1 = 0, c2 = 0, c3 = 0;
    int cbase = (w << 11) + lane;

#define SPQ(Q, D2, TQ, CQ) { bool in_ = (D2) <= TQ; \
    u64 mk_ = __ballot(in_); \
    if (mk_) { uint pos_ = CQ + mbcnt64(mk_); \
        if (in_ && pos_ < CAPSEG) spillIdx[Q][w][pos_] = cidx; \
        CQ += (uint)__popcll(mk_); } }

    {
        float4 p = pts4[cbase];
        for (int it = 0; it < 32; ++it) {
            float4 pn;
            if (it < 31) pn = pts4[cbase + ((it + 1) << 6)];
            uint cidx = (uint)(cbase + (it << 6));
            v2f pw2 = mk2(p.w, p.w), pz2 = mk2(p.z, p.z);
            v2f py2 = mk2(p.y, p.y), px2 = mk2(p.x, p.x);
            v2f sAB = qwAB + pw2;
            sAB = fma2(m2zAB, pz2, sAB);
            sAB = fma2(m2yAB, py2, sAB);
            sAB = fma2(m2xAB, px2, sAB);
            v2f sCD = qwCD + pw2;
            sCD = fma2(m2zCD, pz2, sCD);
            sCD = fma2(m2yCD, py2, sCD);
            sCD = fma2(m2xCD, px2, sCD);
            SPQ(0, sAB.x, T0, c0)
            SPQ(1, sAB.y, T1, c1)
            SPQ(2, sCD.x, T2, c2)
            SPQ(3, sCD.y, T3, c3)
            p = pn;
        }
    }
    if (lane == 0) {
        segcnt[0][w] = c0; segcnt[1][w] = c1; segcnt[2][w] = c2; segcnt[3][w] = c3;
    }
    __syncthreads();

    // ---- refine: wave w selects exact top-32 for query qbase+w ----
    uint sA = min(segcnt[w][0], (uint)CAPSEG), sB = min(segcnt[w][1], (uint)CAPSEG);
    uint sC = min(segcnt[w][2], (uint)CAPSEG), sD = min(segcnt[w][3], (uint)CAPSEG);
    uint b1 = sA, b2 = sA + sB, b3 = sA + sB + sC, total = b3 + sD;
    bool has3 = total > 192, has4 = total > 256, has5 = total > 320;

#define LOADSLOT(S, KK, ID) { \
    uint gpos = (uint)(64 * (S)) + (uint)lane; \
    KK = 0xFFFFFFFFu; ID = 0xFFFFFFFFu; \
    if (gpos < total) { \
        uint seg = (gpos >= b1 ? 1u : 0u) + (gpos >= b2 ? 1u : 0u) + (gpos >= b3 ? 1u : 0u); \
        uint sub = (seg == 0u) ? 0u : (seg == 1u) ? b1 : (seg == 2u) ? b2 : b3; \
        uint idx = spillIdx[w][seg][gpos - sub]; \
        float4 pz = pts4[idx]; \
        float d2 = fmaf(m2x, pz.x, fmaf(m2y, pz.y, fmaf(m2z, pz.z, qw4 + pz.w))); \
        KK = fkey(d2); ID = idx; } }

    uint kk0, kk1, kk2, kk3, kk4, kk5, id0, id1, id2, id3, id4, id5;
    LOADSLOT(0, kk0, id0)
    LOADSLOT(1, kk1, id1)
    LOADSLOT(2, kk2, id2)
    kk3 = 0xFFFFFFFFu; id3 = 0xFFFFFFFFu;
    kk4 = 0xFFFFFFFFu; id4 = 0xFFFFFFFFu;
    kk5 = 0xFFFFFFFFu; id5 = 0xFFFFFFFFu;
    if (has3) LOADSLOT(3, kk3, id3)
    if (has4) LOADSLOT(4, kk4, id4)
    if (has5) LOADSLOT(5, kk5, id5)

    // stage 1: Kc = key of 32nd-smallest spilled candidate (bit-radix, seeded)
    uint Kc = 0x80000000u;
    for (int b = 30; b >= 0; --b) {
        uint cand = Kc | (1u << b);
        uint cnt = (uint)__popcll(__ballot(kk0 < cand))
                 + (uint)__popcll(__ballot(kk1 < cand))
                 + (uint)__popcll(__ballot(kk2 < cand));
        if (has3) cnt += (uint)__popcll(__ballot(kk3 < cand));
        if (has4) cnt += (uint)__popcll(__ballot(kk4 < cand));
        if (has5) cnt += (uint)__popcll(__ballot(kk5 < cand));
        if (cnt < 32u) Kc = cand;
    }
    uint nlt = (uint)__popcll(__ballot(kk0 < Kc)) + (uint)__popcll(__ballot(kk1 < Kc))
             + (uint)__popcll(__ballot(kk2 < Kc)) + (uint)__popcll(__ballot(kk3 < Kc))
             + (uint)__popcll(__ballot(kk4 < Kc)) + (uint)__popcll(__ballot(kk5 < Kc));
    uint ntie = (uint)__popcll(__ballot(kk0 == Kc)) + (uint)__popcll(__ballot(kk1 == Kc))
              + (uint)__popcll(__ballot(kk2 == Kc)) + (uint)__popcll(__ballot(kk3 == Kc))
              + (uint)__popcll(__ballot(kk4 == Kc)) + (uint)__popcll(__ballot(kk5 == Kc));
    uint need = 32u - nlt;
    uint icut = 0xFFFFFFFFu;
    if (ntie != need) {   // tie-break by smallest index (ids unique, 13 bits)
        uint P2 = 0u;
        for (int b = 12; b >= 0; --b) {
            uint cand = P2 | (1u << b);
            uint cnt = (uint)__popcll(__ballot(kk0 == Kc && id0 < cand))
                     + (uint)__popcll(__ballot(kk1 == Kc && id1 < cand))
                     + (uint)__popcll(__ballot(kk2 == Kc && id2 < cand));
            if (has3) cnt += (uint)__popcll(__ballot(kk3 == Kc && id3 < cand));
            if (has4) cnt += (uint)__popcll(__ballot(kk4 == Kc && id4 < cand));
            if (has5) cnt += (uint)__popcll(__ballot(kk5 == Kc && id5 < cand));
            if (cnt < need) P2 = cand;
        }
        icut = P2;
    }

    // ballot-compacted write of the exact 32 selected indices into LDS
    uint dpos = 0;
#define WSEL(KK, ID) { bool acc = (KK < Kc) || (KK == Kc && ID <= icut); \
    u64 mk = __ballot(acc); \
    if (mk) { uint pos = dpos + mbcnt64(mk); \
        if (acc) selEJ[w][pos].y = ID; \
        dpos += (uint)__popcll(mk); } }
    WSEL(kk0, id0) WSEL(kk1, id1) WSEL(kk2, id2)
    WSEL(kk3, id3) WSEL(kk4, id4) WSEL(kk5, id5)

    // ---- fused surround + point branch (same wave, own query) ----
    int q = qbase + w;
    int k = lane & 31;
    uint j = selEJ[w][k].y;            // LDS, same-wave ordered
    float4 pj = pts4[j];
    float dx = qq.x - pj.x, dy = qq.y - pj.y, dz = qq.z - pj.z;
    float dist = sqrtf(fmaf(dx, dx, fmaf(dy, dy, dz * dz)));
    float dmin = dist;
    for (int off = 16; off >= 1; off >>= 1) dmin = fminf(dmin, __shfl_xor(dmin, off));
    float e = expf(dmin - dist);
    float S = e;
    for (int off = 16; off >= 1; off >>= 1) S += __shfl_xor(S, off);
    if (lane < 32) selEJ[w][k].x = __float_as_uint(e);

    int d0 = lane * 2;
    float m0 = -INFINITY, m1 = -INFINITY;
#pragma unroll 4
    for (int kx = 0; kx < 32; ++kx) {
        uint2 ej = selEJ[w][kx];       // broadcast read
        float ek = __uint_as_float(ej.x);
        float2 gv = *(const float2*)&g[ej.y * 128u + (uint)d0];
        m0 = fmaxf(m0, ek * gv.x);
        m1 = fmaxf(m1, ek * gv.y);
    }
    float inv = 1.0f / S;
    float s0 = m0 * inv, s1 = m1 * inv;

    float p0 = bpc[d0 + 0];
    p0 = fmaf(Wpc[(d0 + 0) * 3 + 0], qq.x, p0);
    p0 = fmaf(Wpc[(d0 + 0) * 3 + 1], qq.y, p0);
    p0 = fmaf(Wpc[(d0 + 0) * 3 + 2], qq.z, p0);
    float p1 = bpc[d0 + 1];
    p1 = fmaf(Wpc[(d0 + 1) * 3 + 0], qq.x, p1);
    p1 = fmaf(Wpc[(d0 + 1) * 3 + 1], qq.y, p1);
    p1 = fmaf(Wpc[(d0 + 1) * 3 + 2], qq.z, p1);

    *(float2*)&F[q * 256 + d0] = make_float2(s0, s1);
    *(float2*)&F[q * 256 + 128 + d0] = make_float2(p0, p1);
}

// ---------------------------------------------------------------------------
// out[d][n] = sum_c Wf[d][c] * F[n][c] + bf[d]   (packed-fp32 register tile)
__launch_bounds__(256)
__global__ void k_final(const float* __restrict__ F, const float* __restrict__ Wf,
                        const float* __restrict__ bf, float* __restrict__ out) {
    __shared__ float Fs[256 * 34];
    __shared__ float wfs[32 * 132];
    int t = threadIdx.x;
    int tn = t & 15;
    int td = t >> 4;
    int n0 = blockIdx.x * 32;
    int d0 = td * 8;

    for (int i = t; i < 32 * 256; i += 256) {
        int nn = i >> 8, kk = i & 255;
        Fs[kk * 34 + nn] = F[(n0 + nn) * 256 + kk];
    }

    // acc2[a][j]: a = n-sub (tn*2+a), j = d-pair (d0+2j, d0+2j+1)
    v2f acc2[2][4];
#pragma unroll
    for (int a = 0; a < 2; ++a)
#pragma unroll
        for (int jj = 0; jj < 4; ++jj) acc2[a][jj] = mk2(0.f, 0.f);

    for (int kc = 0; kc < 8; ++kc) {
        __syncthreads();
        for (int i = t; i < 32 * 128; i += 256) {
            int kk = i & 31, d = i >> 5;
            wfs[kk * 132 + d] = Wf[d * 256 + kc * 32 + kk];
        }
        __syncthreads();
#pragma unroll 4
        for (int kk = 0; kk < 32; ++kk) {
            int k = kc * 32 + kk;
            float2 f = *(const float2*)&Fs[k * 34 + tn * 2];
            const float* wr = &wfs[kk * 132 + d0];
            float4 wa = *(const float4*)wr;
            float4 wb = *(const float4*)(wr + 4);
            v2f w0 = mk2(wa.x, wa.y), w1 = mk2(wa.z, wa.w);
            v2f w2 = mk2(wb.x, wb.y), w3 = mk2(wb.z, wb.w);
            v2f fx = mk2(f.x, f.x), fy = mk2(f.y, f.y);
            acc2[0][0] = fma2(fx, w0, acc2[0][0]); acc2[1][0] = fma2(fy, w0, acc2[1][0]);
            acc2[0][1] = fma2(fx, w1, acc2[0][1]); acc2[1][1] = fma2(fy, w1, acc2[1][1]);
            acc2[0][2] = fma2(fx, w2, acc2[0][2]); acc2[1][2] = fma2(fy, w2, acc2[1][2]);
            acc2[0][3] = fma2(fx, w3, acc2[0][3]); acc2[1][3] = fma2(fy, w3, acc2[1][3]);
        }
    }
#pragma unroll
    for (int jj = 0; jj < 4; ++jj) {
        int dA = d0 + 2 * jj, dB = d0 + 2 * jj + 1;
        float bA = bf[dA], bB = bf[dB];
        *(float2*)&out[dA * NPTS + n0 + tn * 2] = make_float2(acc2[0][jj].x + bA, acc2[1][jj].x + bA);
        *(float2*)&out[dB * NPTS + n0 + tn * 2] = make_float2(acc2[0][jj].y + bB, acc2[1][jj].y + bB);
    }
}

// ---------------------------------------------------------------------------
extern "C" void kernel_launch(void* const* d_in, const int* in_sizes, int n_in,
                              void* d_out, int out_size, void* d_ws, size_t ws_size,
                              hipStream_t stream) {
    const float* img_feat = (const float*)d_in[0];
    const float* cloud    = (const float*)d_in[1];
    const float* W1  = (const float*)d_in[2];
    const float* b1  = (const float*)d_in[3];
    const float* W2  = (const float*)d_in[4];
    const float* b2  = (const float*)d_in[5];
    const float* Wp1 = (const float*)d_in[6];
    const float* bp1 = (const float*)d_in[7];
    const float* Wp2 = (const float*)d_in[8];
    const float* bp2 = (const float*)d_in[9];
    const float* Wf  = (const float*)d_in[10];
    const float* bf  = (const float*)d_in[11];
    float* out = (float*)d_out;

    char* ws = (char*)d_ws;
    float4* pts4 = (float4*)(ws + OFF_PTS4);
    float* Wc  = (float*)(ws + OFF_WC);
    float* bc  = (float*)(ws + OFF_BC);
    float* Wpc = (float*)(ws + OFF_WPC);
    float* bpc = (float*)(ws + OFF_BPC);
    float* g   = (float*)(ws + OFF_G);
    float* F   = (float*)(ws + OFF_F);

    k_prep_combine<<<51, 256, 0, stream>>>(cloud, pts4, W1, b1, W2, b2,
                                           Wp1, bp1, Wp2, bp2, Wc, bc, Wpc, bpc);
    k_gfeat<<<NPTS / 16, 256, 0, stream>>>(img_feat, Wc, bc, g);
    k_knn<<<NPTS / 4, 256, 0, stream>>>(pts4, g, Wpc, bpc, F);
    k_final<<<NPTS / 32, 256, 0, stream>>>(F, Wf, bf, out);
}